// Round 1
// baseline (22.327 us; speedup 1.0000x reference)
//
#include <hip/hip_runtime.h>
#include <math.h>

// DRR ray-caster for Registration_2362232013147.
// One pixel is handled by CHUNKS threads (strided step-chunks) for latency
// hiding; partial sums reduced through LDS.
//
// inputs (setup_inputs order):
//   d_in[0] volume   [D,D,D] f32
//   d_in[1] rt_inv   [1,4,4] f32
//   d_in[2] k_inv    [1,3,3] f32
//   d_in[3] sdd      [1]     f32
//   d_in[4] _rot     [1,3]   f32
//   d_in[5] _xyz     [1,3]   f32
//   d_in[6] height   [1]     i32 (unused on device; npix/W)
//   d_in[7] width    [1]     i32
//   d_in[8] n_steps  [1]     i32
// output: img [1,1,H,W] f32

#define BLOCK  256
#define CHUNKS 8
#define PPB    (BLOCK / CHUNKS)   // 32 pixels per block

__global__ __launch_bounds__(BLOCK) void drr_kernel(
    const float* __restrict__ vol,
    const float* __restrict__ rt_inv,
    const float* __restrict__ k_inv,
    const float* __restrict__ sdd_p,
    const float* __restrict__ rot_p,
    const float* __restrict__ xyz_p,
    const int*   __restrict__ width_p,
    const int*   __restrict__ nsteps_p,
    float*       __restrict__ out,
    const int npix, const int D)
{
    const int tid   = (int)threadIdx.x;
    const int slot  = tid & (PPB - 1);   // pixel slot within block
    const int chunk = tid / PPB;         // step-chunk id [0, CHUNKS)
    const int p     = (int)blockIdx.x * PPB + slot;

    float acc    = 0.0f;
    float seglen = 0.0f;

    if (p < npix) {
        const int W = *width_p;
        const int n = *nsteps_p;
        const int h = p / W;
        const int w = p - h * W;

        // ---- pose: Rodrigues(_rot), then T = P @ rt_inv ----
        const float rx = rot_p[0], ry = rot_p[1], rz = rot_p[2];
        const float th2 = rx*rx + ry*ry + rz*rz;
        const float th  = sqrtf(th2 + 1e-30f);
        const float a   = (th2 < 1e-12f) ? (1.0f - th2 * (1.0f/6.0f))  : (sinf(th) / th);
        const float b   = (th2 < 1e-12f) ? (0.5f - th2 * (1.0f/24.0f)) : ((1.0f - cosf(th)) / th2);
        // R = I + a*K + b*K^2, K = skew(rot)
        float Rm[3][3];
        Rm[0][0] = 1.0f + b * (-(ry*ry + rz*rz));
        Rm[0][1] = a * (-rz) + b * (rx*ry);
        Rm[0][2] = a * ( ry) + b * (rx*rz);
        Rm[1][0] = a * ( rz) + b * (rx*ry);
        Rm[1][1] = 1.0f + b * (-(rx*rx + rz*rz));
        Rm[1][2] = a * (-rx) + b * (ry*rz);
        Rm[2][0] = a * (-ry) + b * (rx*rz);
        Rm[2][1] = a * ( rx) + b * (ry*rz);
        Rm[2][2] = 1.0f + b * (-(rx*rx + ry*ry));
        const float tv[3] = { xyz_p[0], xyz_p[1], xyz_p[2] };
        // T = [[R t];[0 1]] @ rt_inv  (rt_inv row-major 4x4)
        const float* M = rt_inv;
        float Rw[3][3], tw[3];
        #pragma unroll
        for (int i = 0; i < 3; ++i) {
            #pragma unroll
            for (int j = 0; j < 4; ++j) {
                float s = Rm[i][0]*M[0*4+j] + Rm[i][1]*M[1*4+j]
                        + Rm[i][2]*M[2*4+j] + tv[i]*M[3*4+j];
                if (j < 3) Rw[i][j] = s; else tw[i] = s;
            }
        }

        const float sdd = sdd_p[0];
        const float u = (float)w + 0.5f;
        const float v = (float)h + 0.5f;
        // cam = (k_inv @ [u,v,1]) * sdd
        const float cx = (k_inv[0]*u + k_inv[1]*v + k_inv[2]) * sdd;
        const float cy = (k_inv[3]*u + k_inv[4]*v + k_inv[5]) * sdd;
        const float cz = (k_inv[6]*u + k_inv[7]*v + k_inv[8]) * sdd;
        // tgt = Rw@cam + tw ; src = tw ; ray = tgt - src (keep reference order)
        const float tgx = Rw[0][0]*cx + Rw[0][1]*cy + Rw[0][2]*cz + tw[0];
        const float tgy = Rw[1][0]*cx + Rw[1][1]*cy + Rw[1][2]*cz + tw[1];
        const float tgz = Rw[2][0]*cx + Rw[2][1]*cy + Rw[2][2]*cz + tw[2];
        const float rayx = tgx - tw[0];
        const float rayy = tgy - tw[1];
        const float rayz = tgz - tw[2];
        const float fn = (float)n;
        seglen = sqrtf(rayx*rayx + rayy*rayy + rayz*rayz) / fn;

        const float c    = 0.5f * (float)(D - 1);   // 127.5
        const float dimf = (float)(D - 1);          // 255.0
        // idx_axis(alpha) = (tw + alpha*ray) + c  -> q + alpha*ray
        const float qx = tw[0] + c, qy = tw[1] + c, qz = tw[2] + c;

        // analytic alpha range where all axes are inside [0, dimf]
        float alo = -1e30f, ahi = 1e30f;
        bool empty = false;
        {
            const float qs[3] = { qx, qy, qz };
            const float rs[3] = { rayx, rayy, rayz };
            #pragma unroll
            for (int ax = 0; ax < 3; ++ax) {
                const float q = qs[ax], r = rs[ax];
                if (fabsf(r) < 1e-20f) {
                    if (q < 0.0f || q > dimf) empty = true;
                } else {
                    const float t0 = (0.0f - q) / r;
                    const float t1 = (dimf - q) / r;
                    alo = fmaxf(alo, fminf(t0, t1));
                    ahi = fminf(ahi, fmaxf(t0, t1));
                }
            }
        }

        if (!empty && alo <= ahi) {
            // step range: alpha_i = (i+0.5)/n in [alo, ahi]; widen by 1 for
            // float safety, keep the exact per-step inside check below.
            int ilo = (int)ceilf (alo * fn - 0.5f) - 1;
            int ihi = (int)floorf(ahi * fn - 0.5f) + 1;
            ilo = max(ilo, 0);
            ihi = min(ihi, n - 1);
            // first step index >= ilo congruent to this thread's chunk
            int start = ilo + ((chunk - ilo) % CHUNKS + CHUNKS) % CHUNKS;

            const float inv_n = 1.0f / fn;
            const int DD = D * D;
            for (int i = start; i <= ihi; i += CHUNKS) {
                const float alpha = ((float)i + 0.5f) * inv_n;
                const float px = fmaf(alpha, rayx, qx);
                const float py = fmaf(alpha, rayy, qy);
                const float pz = fmaf(alpha, rayz, qz);
                const bool inside = (px >= 0.0f) & (px <= dimf)
                                  & (py >= 0.0f) & (py <= dimf)
                                  & (pz >= 0.0f) & (pz <= dimf);
                if (!inside) continue;
                const float fxf = floorf(px), fyf = floorf(py), fzf = floorf(pz);
                const float fx = px - fxf, fy = py - fyf, fz = pz - fzf;
                int x0 = min(max((int)fxf, 0), D - 2);
                int y0 = min(max((int)fyf, 0), D - 2);
                int z0 = min(max((int)fzf, 0), D - 2);
                const float* b000 = vol + (size_t)x0 * DD + (size_t)y0 * D + z0;
                const float c000 = b000[0];
                const float c001 = b000[1];
                const float c010 = b000[D];
                const float c011 = b000[D + 1];
                const float c100 = b000[DD];
                const float c101 = b000[DD + 1];
                const float c110 = b000[DD + D];
                const float c111 = b000[DD + D + 1];
                const float c00 = c000 * (1.0f - fz) + c001 * fz;
                const float c01 = c010 * (1.0f - fz) + c011 * fz;
                const float c10 = c100 * (1.0f - fz) + c101 * fz;
                const float c11 = c110 * (1.0f - fz) + c111 * fz;
                const float c0  = c00 * (1.0f - fy) + c01 * fy;
                const float c1  = c10 * (1.0f - fy) + c11 * fy;
                acc += c0 * (1.0f - fx) + c1 * fx;
            }
        }
    }

    // reduce CHUNKS partials per pixel
    __shared__ float red[BLOCK];
    red[tid] = acc;
    __syncthreads();
    if (tid < PPB) {
        float s = 0.0f;
        #pragma unroll
        for (int k = 0; k < CHUNKS; ++k) s += red[tid + k * PPB];
        if (p < npix) out[p] = s * seglen;
    }
}

extern "C" void kernel_launch(void* const* d_in, const int* in_sizes, int n_in,
                              void* d_out, int out_size, void* d_ws, size_t ws_size,
                              hipStream_t stream) {
    const float* vol    = (const float*)d_in[0];
    const float* rt_inv = (const float*)d_in[1];
    const float* k_inv  = (const float*)d_in[2];
    const float* sdd    = (const float*)d_in[3];
    const float* rot    = (const float*)d_in[4];
    const float* xyz    = (const float*)d_in[5];
    const int*   width  = (const int*)d_in[7];
    const int*   nsteps = (const int*)d_in[8];
    float* out = (float*)d_out;

    const int npix = out_size;                       // H*W
    const int D    = (int)lround(cbrt((double)in_sizes[0]));

    const int blocks = (npix + PPB - 1) / PPB;
    drr_kernel<<<blocks, BLOCK, 0, stream>>>(
        vol, rt_inv, k_inv, sdd, rot, xyz, width, nsteps, out, npix, D);
}